// Round 6
// baseline (80.495 us; speedup 1.0000x reference)
//
#include <hip/hip_runtime.h>
#include <math.h>
#include <stdint.h>

#define NIMG 8
#define HH 1024
#define WW 1024
#define NPIX (HH*WW)
#define PAIRS 10000
#define STRIP 8
#define NSTRIPS 128          // strips per image (rows 1..1022, 8 rows each)
#define SBLK 157             // ceil(PAIRS*4 / 256) sample blocks per image
#define PSTRIDE 640          // per-image partial-slot stride (>= SBLK*4 = 628)

// ws layout (floats; every slot plainly overwritten each launch — no init):
// [OFF_EDGE .. +NIMG*NSTRIPS)   per-strip squared-sobel max   (1024)
// [OFF_MD   .. +NIMG*PSTRIDE)   per-wave maxdiff partials
// [OFF_UN   .. +NIMG*PSTRIDE)   per-wave unequal-loss partials
// [OFF_CNT  .. +NIMG*PSTRIDE)   per-wave count partials
// [OFF_RES  .. +16)             per-image {loss, cnt}
// byte 131072: recs float2[NIMG*PAIRS*4] = {d2, ad} per (pair, segment-lane)
#define OFF_EDGE 0
#define OFF_MD   1024
#define OFF_UN   (1024 + NIMG*PSTRIDE)
#define OFF_CNT  (1024 + 2*NIMG*PSTRIDE)
#define OFF_RES  (1024 + 3*NIMG*PSTRIDE)

__device__ __forceinline__ uint64_t mix64(uint64_t x){
    x += 0x9E3779B97F4A7C15ull;
    x = (x ^ (x >> 30)) * 0xBF58476D1CE4E5B9ull;
    x = (x ^ (x >> 27)) * 0x94D049BB133111EBull;
    return x ^ (x >> 31);
}

__device__ __forceinline__ float block_reduce_max(float v, float* sm){
    for (int off = 32; off; off >>= 1)
        v = fmaxf(v, __shfl_down(v, off));
    int wv = threadIdx.x >> 6, lane = threadIdx.x & 63;
    int nw = blockDim.x >> 6;
    if (lane == 0) sm[wv] = v;
    __syncthreads();
    if (threadIdx.x == 0){
        float m = sm[0];
        for (int i = 1; i < nw; ++i) m = fmaxf(m, sm[i]);
        sm[0] = m;
    }
    __syncthreads();
    float r = sm[0];
    __syncthreads();
    return r;
}

__device__ __forceinline__ float block_reduce_sum(float v, float* sm){
    for (int off = 32; off; off >>= 1)
        v += __shfl_down(v, off);
    int wv = threadIdx.x >> 6, lane = threadIdx.x & 63;
    int nw = blockDim.x >> 6;
    if (lane == 0) sm[wv] = v;
    __syncthreads();
    if (threadIdx.x == 0){
        float m = sm[0];
        for (int i = 1; i < nw; ++i) m += sm[i];
        sm[0] = m;
    }
    __syncthreads();
    float r = sm[0];
    __syncthreads();
    return r;
}

__device__ __forceinline__ void sobel_at(const float* __restrict__ x, int r, int c,
                                         float& gx, float& gy){
    const float* p0 = x + (size_t)(r-1)*WW + c;
    const float* p1 = x + (size_t)r*WW + c;
    const float* p2 = x + (size_t)(r+1)*WW + c;
    float a = p0[-1], b = p0[0], cc = p0[1];
    float d = p1[-1],             e = p1[1];
    float f = p2[-1], g = p2[0], h = p2[1];
    gx = (cc - a) + 2.0f*(e - d) + (h - f);
    gy = (a + 2.0f*b + cc) - (f + 2.0f*g + h);
}

__device__ __forceinline__ void load16(const float* __restrict__ p, float* d){
    const float4* q = (const float4*)p;
    float4 v0 = q[0], v1 = q[1], v2 = q[2], v3 = q[3];
    d[0]=v0.x; d[1]=v0.y; d[2]=v0.z; d[3]=v0.w;
    d[4]=v1.x; d[5]=v1.y; d[6]=v1.z; d[7]=v1.w;
    d[8]=v2.x; d[9]=v2.y; d[10]=v2.z; d[11]=v2.w;
    d[12]=v3.x; d[13]=v3.y; d[14]=v3.z; d[15]=v3.w;
}

// R3-proven: one wave owns a 1024-wide row span (16 cols/lane), rolls 3 rows
// in registers, separable sobel, shuffles for column neighbors, squared mag.
__global__ __launch_bounds__(256) void edgemax_kernel(const float* __restrict__ images,
                                                      float* __restrict__ edgepart){
    int img  = blockIdx.y;
    const float* x = images + (size_t)img * 3 * NPIX;   // channel 0
    int wv   = threadIdx.x >> 6;
    int lane = threadIdx.x & 63;
    int strip = blockIdx.x * 4 + wv;                    // 0..127
    int r0 = 1 + strip * STRIP;
    int r1 = min(r0 + STRIP - 1, HH - 2);
    int c0 = lane * 16;

    float a[16], b[16], n[16];
    load16(x + (size_t)(r0-1)*WW + c0, a);
    load16(x + (size_t)r0*WW + c0, b);

    float m = 0.0f;
    for (int r = r0; r <= r1; ++r){
        load16(x + (size_t)(r+1)*WW + c0, n);
        float sx[16], dy[16];
        #pragma unroll
        for (int i = 0; i < 16; ++i){
            sx[i] = a[i] + 2.0f*b[i] + n[i];
            dy[i] = a[i] - n[i];
        }
        float sxl = __shfl_up(sx[15], 1);
        float sxr = __shfl_down(sx[0], 1);
        float dyl = __shfl_up(dy[15], 1);
        float dyr = __shfl_down(dy[0], 1);
        #pragma unroll
        for (int j = 0; j < 16; ++j){
            float sl = (j == 0)  ? sxl : sx[j-1];
            float sr = (j == 15) ? sxr : sx[j+1];
            float dl = (j == 0)  ? dyl : dy[j-1];
            float dr = (j == 15) ? dyr : dy[j+1];
            float gx = sr - sl;
            float gy = dl + 2.0f*dy[j] + dr;
            float e2 = gx*gx + gy*gy;
            int c = c0 + j;
            if (c >= 1 && c <= WW-2) m = fmaxf(m, e2);
        }
        #pragma unroll
        for (int i = 0; i < 16; ++i){ a[i] = b[i]; b[i] = n[i]; }
    }
    for (int off = 32; off; off >>= 1)
        m = fmaxf(m, __shfl_down(m, off));
    if (lane == 0)
        edgepart[img * NSTRIPS + strip] = m;
}

// 4 lanes cooperate on one pair: lane sub=g&3 evaluates attempt (round+sub);
// ballot-nibble picks the LOWEST passing attempt (identical selection order
// to the serial rejection loop -> identical distribution).
__global__ __launch_bounds__(256) void sample_kernel(
                               const float* __restrict__ inputs,
                               const float* __restrict__ targets,
                               const float* __restrict__ images,
                               const float* __restrict__ depth_gt,
                               float* __restrict__ ws,
                               float2* __restrict__ recs){
    __shared__ float sred[4];
    int img  = blockIdx.y;
    int jb   = blockIdx.x;
    int tid  = threadIdx.x;
    int lane = tid & 63;
    int grpb = lane & ~3;                 // group base lane
    int g    = jb * 256 + tid;            // 0..40191
    int j    = g >> 2;                    // pair index
    int sub  = g & 3;
    const float* x   = images   + (size_t)img * 3 * NPIX;
    const float* inp = inputs   + (size_t)img * NPIX;
    const float* tgt = targets  + (size_t)img * NPIX;
    const float* dgt = depth_gt + (size_t)img * NPIX;

    float ev = 0.0f;
    if (tid < NSTRIPS) ev = ws[OFF_EDGE + img * NSTRIPS + tid];
    float thr2 = 0.01f * block_reduce_max(ev, sred);

    bool inrange = (j < PAIRS);
    uint64_t base = ((uint64_t)(img * PAIRS + j)) << 10;
    bool pdir = (mix64(((uint64_t)(NIMG * PAIRS + img)) << 10) & 1ull) != 0ull;

    // ---- group-parallel rejection sampling ----
    bool done = !inrange;
    int selr = 0, selc = 0;
    float selgx = 0.f, selgy = 0.f, sele2 = 1.f;
    bool found = false;

    for (int rb = 0; rb < 900; rb += 4){
        if (__all(done)) break;
        bool p = false;
        int rr = 0, cc = 0; float gx = 0.f, gy = 0.f, e2 = 0.f;
        if (!done){
            uint64_t u = mix64(base + (uint64_t)(rb + sub));
            uint32_t pix = (uint32_t)(u >> 44);
            rr = (int)(pix >> 10);
            cc = (int)(pix & (WW - 1));
            int rl = min(max(rr, 1), HH-2);
            int cl = min(max(cc, 1), WW-2);
            sobel_at(x, rl, cl, gx, gy);
            e2 = gx*gx + gy*gy;
            float dg = dgt[rl*WW + cl];
            float tg = tgt[rl*WW + cl];
            p = (rr == rl) && (cc == cl) && (e2 >= thr2) &&
                (dg > -0.001f && dg < 80.0f && tg != 80.0f);
        }
        unsigned long long bal = __ballot(p);
        if (!done){
            unsigned nib = (unsigned)((bal >> grpb) & 0xFull);
            if (nib){
                int w = __ffs((int)nib) - 1;      // winning sub (lowest attempt)
                int src = grpb + w;
                selr  = __shfl(rr, src);
                selc  = __shfl(cc, src);
                selgx = __shfl(gx, src);
                selgy = __shfl(gy, src);
                sele2 = __shfl(e2, src);
                found = true;
                done  = true;
            }
        }
    }

    // ---- endpoint per lane ----
    float mdiff = 0.0f, un = 0.0f, cntv = 0.0f;
    float d2 = 0.0f, ad = 0.0f;
    bool inb = false;
    float tA = 0.f, iA = 0.f;

    if (found){
        float inv = rsqrtf(sele2);
        float cmul = selgx * inv;
        float rmul = selgy * inv;
        if (!pdir) cmul = -cmul;

        uint64_t uu = mix64(base + 1000ull + (uint64_t)(sub >> 1));
        uint32_t half = (sub & 1) ? (uint32_t)(uu >> 32) : (uint32_t)(uu & 0xFFFFFFFFull);
        float dist = (float)(2u + half % 29u) * ((sub < 2) ? -1.0f : 1.0f);

        int cc2 = selc + (int)rintf(dist * cmul);
        int rr2 = selr + (int)rintf(dist * rmul);
        inb = (cc2 >= 0 && cc2 <= WW-1 && rr2 >= 0 && rr2 <= HH-1);
        int p = min(max(rr2, 0), HH-1)*WW + min(max(cc2, 0), WW-1);
        tA = tgt[p];
        iA = inp[p];
    }
    unsigned long long vb = __ballot(found && inb);
    bool valid = found && (((vb >> grpb) & 0xFull) == 0xFull);

    float tB = __shfl_down(tA, 1);
    float iB = __shfl_down(iA, 1);

    if (valid && sub < 3){
        float ratio = (tA + 1e-6f) / (tB + 1e-6f);
        float adk = fabsf(tA - tB);
        mdiff = adk;
        bool eq = (ratio < 1.03f) && (ratio > 0.9708737864077669f);
        if (eq){
            float d = iA - iB;
            d2 = d*d; ad = adk;
        } else {
            float lab = (ratio >= 1.03f) ? 1.0f : -1.0f;
            un = log1pf(expf((iB - iA) * lab));
        }
    }
    if (valid && sub == 0) cntv = 3.0f;

    if (inrange)
        recs[(size_t)img * PAIRS * 4 + g] = make_float2(d2, ad);

    // per-wave partials (plain stores)
    float m_ = mdiff, u_ = un, c_ = cntv;
    for (int off = 32; off; off >>= 1){
        m_ = fmaxf(m_, __shfl_down(m_, off));
        u_ += __shfl_down(u_, off);
        c_ += __shfl_down(c_, off);
    }
    if (lane == 0){
        int slot = jb*4 + (tid >> 6);
        ws[OFF_MD  + img * PSTRIDE + slot] = m_;
        ws[OFF_UN  + img * PSTRIDE + slot] = u_;
        ws[OFF_CNT + img * PSTRIDE + slot] = c_;
    }
}

// One block per image: reduce partials, coalesced scan of records, finish loss.
__global__ __launch_bounds__(512) void finish_kernel(
                               float* __restrict__ ws,
                               const float2* __restrict__ recs){
    __shared__ float sm[8];
    int img = blockIdx.x;
    int tid = threadIdx.x;

    float mv = 0.0f, uv = 0.0f, cv = 0.0f;
    for (int s = tid; s < SBLK*4; s += 512){
        mv = fmaxf(mv, ws[OFF_MD + img * PSTRIDE + s]);
        uv += ws[OFF_UN  + img * PSTRIDE + s];
        cv += ws[OFF_CNT + img * PSTRIDE + s];
    }
    float md = block_reduce_max(mv, sm);
    float inv = 1.0f / (md + 1e-6f);

    float loss = 0.0f;
    for (int r = tid; r < PAIRS*4; r += 512){
        float2 A = recs[(size_t)img * PAIRS * 4 + r];
        loss += A.x * expf(-A.y * inv);
    }
    loss = block_reduce_sum(loss + uv, sm);
    float cnt = block_reduce_sum(cv, sm);
    if (tid == 0){
        ws[OFF_RES + img*2 + 0] = loss;
        ws[OFF_RES + img*2 + 1] = cnt;
    }
}

__global__ void finalize_kernel(const float* __restrict__ ws,
                                float* __restrict__ out){
    if (threadIdx.x == 0){
        float tl = 0.0f, tc = 0.0f;
        for (int i = 0; i < NIMG; ++i){
            float loss = ws[OFF_RES + i*2 + 0];
            float cnt  = ws[OFF_RES + i*2 + 1];
            tl += loss / fmaxf(cnt, 1.0f);   // ALPHA = 1
            tc += cnt;
        }
        out[0] = tl / (float)NIMG;
        out[1] = tc / (float)NIMG;
    }
}

extern "C" void kernel_launch(void* const* d_in, const int* in_sizes, int n_in,
                              void* d_out, int out_size, void* d_ws, size_t ws_size,
                              hipStream_t stream) {
    const float* inputs  = (const float*)d_in[0];
    const float* targets = (const float*)d_in[1];
    const float* images  = (const float*)d_in[2];
    const float* depth   = (const float*)d_in[3];
    float* out = (float*)d_out;

    float* ws    = (float*)d_ws;
    float2* recs = (float2*)((char*)d_ws + 131072);

    hipLaunchKernelGGL(edgemax_kernel, dim3(NSTRIPS/4, NIMG), dim3(256), 0, stream,
                       images, ws + OFF_EDGE);
    hipLaunchKernelGGL(sample_kernel, dim3(SBLK, NIMG), dim3(256), 0, stream,
                       inputs, targets, images, depth, ws, recs);
    hipLaunchKernelGGL(finish_kernel, dim3(NIMG), dim3(512), 0, stream, ws, recs);
    hipLaunchKernelGGL(finalize_kernel, dim3(1), dim3(64), 0, stream, ws, out);
}

// Round 7
// 56.186 us; speedup vs baseline: 1.4327x; 1.4327x over previous
//
#include <hip/hip_runtime.h>
#include <math.h>
#include <stdint.h>

#define NIMG 8
#define HH 1024
#define WW 1024
#define NPIX (HH*WW)
#define PAIRS 10000
#define STRIP 8
#define NSTRIPS 128          // strips per image (rows 1..1022, 8 rows each)
#define S1BLOCKS 40          // sample blocks per image
#define WSLOTS (S1BLOCKS*4)  // per-wave partial slots per image (160)

// ws layout (floats; every slot plainly overwritten each launch — no init):
// [OFF_EDGE .. +NIMG*NSTRIPS)  per-strip squared-sobel max   (1024)
// [OFF_MD   .. +NIMG*WSLOTS)   per-wave maxdiff partials     (1280)
// [OFF_RES  .. +16)            per-image {loss, cnt}
// byte 65536:                recsA [NIMG*PAIRS] float4 (d2_0,d2_1,d2_2,un)
// byte 65536+NIMG*PAIRS*16:  recsB [NIMG*PAIRS] float4 (ad_0,ad_1,ad_2,cnt)
#define OFF_EDGE 0
#define OFF_MD   1024
#define OFF_RES  4096

__device__ __forceinline__ uint64_t mix64(uint64_t x){
    x += 0x9E3779B97F4A7C15ull;
    x = (x ^ (x >> 30)) * 0xBF58476D1CE4E5B9ull;
    x = (x ^ (x >> 27)) * 0x94D049BB133111EBull;
    return x ^ (x >> 31);
}

__device__ __forceinline__ float block_reduce_max(float v, float* sm){
    for (int off = 32; off; off >>= 1)
        v = fmaxf(v, __shfl_down(v, off));
    int wv = threadIdx.x >> 6, lane = threadIdx.x & 63;
    int nw = blockDim.x >> 6;
    if (lane == 0) sm[wv] = v;
    __syncthreads();
    if (threadIdx.x == 0){
        float m = sm[0];
        for (int i = 1; i < nw; ++i) m = fmaxf(m, sm[i]);
        sm[0] = m;
    }
    __syncthreads();
    float r = sm[0];
    __syncthreads();
    return r;
}

__device__ __forceinline__ float block_reduce_sum(float v, float* sm){
    for (int off = 32; off; off >>= 1)
        v += __shfl_down(v, off);
    int wv = threadIdx.x >> 6, lane = threadIdx.x & 63;
    int nw = blockDim.x >> 6;
    if (lane == 0) sm[wv] = v;
    __syncthreads();
    if (threadIdx.x == 0){
        float m = sm[0];
        for (int i = 1; i < nw; ++i) m += sm[i];
        sm[0] = m;
    }
    __syncthreads();
    float r = sm[0];
    __syncthreads();
    return r;
}

__device__ __forceinline__ void sobel_at(const float* __restrict__ x, int r, int c,
                                         float& gx, float& gy){
    const float* p0 = x + (size_t)(r-1)*WW + c;
    const float* p1 = x + (size_t)r*WW + c;
    const float* p2 = x + (size_t)(r+1)*WW + c;
    float a = p0[-1], b = p0[0], cc = p0[1];
    float d = p1[-1],             e = p1[1];
    float f = p2[-1], g = p2[0], h = p2[1];
    gx = (cc - a) + 2.0f*(e - d) + (h - f);
    gy = (a + 2.0f*b + cc) - (f + 2.0f*g + h);
}

__device__ __forceinline__ void load16(const float* __restrict__ p, float* d){
    const float4* q = (const float4*)p;
    float4 v0 = q[0], v1 = q[1], v2 = q[2], v3 = q[3];
    d[0]=v0.x; d[1]=v0.y; d[2]=v0.z; d[3]=v0.w;
    d[4]=v1.x; d[5]=v1.y; d[6]=v1.z; d[7]=v1.w;
    d[8]=v2.x; d[9]=v2.y; d[10]=v2.z; d[11]=v2.w;
    d[12]=v3.x; d[13]=v3.y; d[14]=v3.z; d[15]=v3.w;
}

// One wave owns a 1024-wide row span (16 cols/lane), rolls 3 rows in registers,
// separable sobel, cross-lane neighbors via shuffles, max of SQUARED magnitude.
__global__ __launch_bounds__(256) void edgemax_kernel(const float* __restrict__ images,
                                                      float* __restrict__ edgepart){
    int img  = blockIdx.y;
    const float* x = images + (size_t)img * 3 * NPIX;   // channel 0
    int wv   = threadIdx.x >> 6;
    int lane = threadIdx.x & 63;
    int strip = blockIdx.x * 4 + wv;                    // 0..127
    int r0 = 1 + strip * STRIP;
    int r1 = min(r0 + STRIP - 1, HH - 2);
    int c0 = lane * 16;

    float a[16], b[16], n[16];
    load16(x + (size_t)(r0-1)*WW + c0, a);
    load16(x + (size_t)r0*WW + c0, b);

    float m = 0.0f;
    for (int r = r0; r <= r1; ++r){
        load16(x + (size_t)(r+1)*WW + c0, n);
        float sx[16], dy[16];
        #pragma unroll
        for (int i = 0; i < 16; ++i){
            sx[i] = a[i] + 2.0f*b[i] + n[i];
            dy[i] = a[i] - n[i];
        }
        float sxl = __shfl_up(sx[15], 1);
        float sxr = __shfl_down(sx[0], 1);
        float dyl = __shfl_up(dy[15], 1);
        float dyr = __shfl_down(dy[0], 1);
        #pragma unroll
        for (int j = 0; j < 16; ++j){
            float sl = (j == 0)  ? sxl : sx[j-1];
            float sr = (j == 15) ? sxr : sx[j+1];
            float dl = (j == 0)  ? dyl : dy[j-1];
            float dr = (j == 15) ? dyr : dy[j+1];
            float gx = sr - sl;
            float gy = dl + 2.0f*dy[j] + dr;
            float e2 = gx*gx + gy*gy;
            int c = c0 + j;
            if (c >= 1 && c <= WW-2) m = fmaxf(m, e2);
        }
        #pragma unroll
        for (int i = 0; i < 16; ++i){ a[i] = b[i]; b[i] = n[i]; }
    }
    for (int off = 32; off; off >>= 1)
        m = fmaxf(m, __shfl_down(m, off));
    if (lane == 0)
        edgepart[img * NSTRIPS + strip] = m;
}

// 1 thread per pair, serial rejection (line-minimal: expected 1.15 sobels/pair;
// dgt/tgt loaded only after the edge test passes). Single pass: classification
// spilled to records so no second scattered pass is needed.
__global__ __launch_bounds__(256) void sample_kernel(
                               const float* __restrict__ inputs,
                               const float* __restrict__ targets,
                               const float* __restrict__ images,
                               const float* __restrict__ depth_gt,
                               float* __restrict__ ws,
                               float4* __restrict__ recsA,
                               float4* __restrict__ recsB){
    __shared__ float sred[4];
    int img = blockIdx.y;
    int jb  = blockIdx.x;
    int tid = threadIdx.x;
    int j   = jb * 256 + tid;
    const float* x   = images   + (size_t)img * 3 * NPIX;
    const float* inp = inputs   + (size_t)img * NPIX;
    const float* tgt = targets  + (size_t)img * NPIX;
    const float* dgt = depth_gt + (size_t)img * NPIX;

    float ev = 0.0f;
    if (tid < NSTRIPS) ev = ws[OFF_EDGE + img * NSTRIPS + tid];
    float thr2 = 0.01f * block_reduce_max(ev, sred);

    float mdiff = 0.0f;
    float4 recA = make_float4(0.f, 0.f, 0.f, 0.f);   // d2[3], un
    float4 recB = make_float4(0.f, 0.f, 0.f, 0.f);   // ad[3], cnt

    if (j < PAIRS){
        uint64_t base = ((uint64_t)(img * PAIRS + j)) << 10;
        bool pdir = (mix64(((uint64_t)(NIMG * PAIRS + img)) << 10) & 1ull) != 0ull;

        int sh = -1, sw = -1;
        float gxs = 0.f, gys = 0.f, e2s = 1.f;
        for (int att = 0; att < 900; ++att){
            uint64_t u = mix64(base + (uint64_t)att);
            uint32_t pix = (uint32_t)(u >> 44);       // 20-bit uniform
            int r = (int)(pix >> 10);
            int c = (int)(pix & (WW - 1));
            if (r == 0 || r >= HH-1 || c == 0 || c >= WW-1) continue;
            float gx, gy;
            sobel_at(x, r, c, gx, gy);
            float e2 = gx*gx + gy*gy;
            if (!(e2 >= thr2)) continue;
            float dg = dgt[r*WW + c];
            float tg = tgt[r*WW + c];
            if (!(dg > -0.001f && dg < 80.0f && tg != 80.0f)) continue;
            sh = r; sw = c; gxs = gx; gys = gy; e2s = e2;
            break;
        }

        if (sh >= 0){
            float inv = rsqrtf(e2s);
            float cmul = gxs * inv;
            float rmul = gys * inv;
            if (!pdir) cmul = -cmul;

            uint64_t u0 = mix64(base + 1000ull);
            uint64_t u1 = mix64(base + 1001ull);
            float dist[4];
            dist[0] = -(float)(2u + (uint32_t)(u0 & 0xFFFFFFFFull) % 29u);
            dist[1] = -(float)(2u + (uint32_t)(u0 >> 32) % 29u);
            dist[2] =  (float)(2u + (uint32_t)(u1 & 0xFFFFFFFFull) % 29u);
            dist[3] =  (float)(2u + (uint32_t)(u1 >> 32) % 29u);

            int rowc[4], colc[4];
            bool valid = true;
            #pragma unroll
            for (int k = 0; k < 4; ++k){
                int cc2 = sw + (int)rintf(dist[k] * cmul);
                int rr2 = sh + (int)rintf(dist[k] * rmul);
                if (cc2 < 0 || cc2 > WW-1 || rr2 < 0 || rr2 > HH-1) valid = false;
                colc[k] = min(max(cc2, 0), WW-1);
                rowc[k] = min(max(rr2, 0), HH-1);
            }

            if (valid){
                float t4[4], i4[4];
                #pragma unroll
                for (int k = 0; k < 4; ++k){
                    int p = rowc[k]*WW + colc[k];
                    t4[k] = tgt[p];
                    i4[k] = inp[p];
                }
                float d2a[3], ada[3];
                float un = 0.0f;
                #pragma unroll
                for (int k = 0; k < 3; ++k){
                    float tA = t4[k], tB = t4[k+1];
                    float ratio = (tA + 1e-6f) / (tB + 1e-6f);
                    float adk = fabsf(tA - tB);
                    mdiff = fmaxf(mdiff, adk);
                    bool eq = (ratio < 1.03f) && (ratio > 0.9708737864077669f);
                    if (eq){
                        float d = i4[k] - i4[k+1];
                        d2a[k] = d*d; ada[k] = adk;
                    } else {
                        d2a[k] = 0.f; ada[k] = 0.f;
                        float lab = (ratio >= 1.03f) ? 1.0f : -1.0f;
                        un += log1pf(expf((i4[k+1] - i4[k]) * lab));
                    }
                }
                recA = make_float4(d2a[0], d2a[1], d2a[2], un);
                recB = make_float4(ada[0], ada[1], ada[2], 3.0f);
            }
        }
        recsA[img * PAIRS + j] = recA;
        recsB[img * PAIRS + j] = recB;
    }

    for (int off = 32; off; off >>= 1)
        mdiff = fmaxf(mdiff, __shfl_down(mdiff, off));
    if ((tid & 63) == 0)
        ws[OFF_MD + img * WSLOTS + jb*4 + (tid >> 6)] = mdiff;
}

// One block per image: reduce maxdiff partials, coalesced scan, finish loss.
__global__ __launch_bounds__(256) void finish_kernel(
                               float* __restrict__ ws,
                               const float4* __restrict__ recsA,
                               const float4* __restrict__ recsB){
    __shared__ float sred[4];
    int img = blockIdx.x;
    int tid = threadIdx.x;

    float mv = 0.0f;
    if (tid < WSLOTS) mv = ws[OFF_MD + img * WSLOTS + tid];
    float md = block_reduce_max(mv, sred);
    float inv = 1.0f / (md + 1e-6f);

    float loss = 0.0f, cnt = 0.0f;
    for (int r = tid; r < PAIRS; r += 256){
        float4 A = recsA[img * PAIRS + r];
        float4 B = recsB[img * PAIRS + r];
        loss += A.w
              + A.x * expf(-B.x * inv)
              + A.y * expf(-B.y * inv)
              + A.z * expf(-B.z * inv);
        cnt  += B.w;
    }
    loss = block_reduce_sum(loss, sred);
    cnt  = block_reduce_sum(cnt, sred);
    if (tid == 0){
        ws[OFF_RES + img*2 + 0] = loss;
        ws[OFF_RES + img*2 + 1] = cnt;
    }
}

__global__ void finalize_kernel(const float* __restrict__ ws,
                                float* __restrict__ out){
    if (threadIdx.x == 0){
        float tl = 0.0f, tc = 0.0f;
        for (int i = 0; i < NIMG; ++i){
            float loss = ws[OFF_RES + i*2 + 0];
            float cnt  = ws[OFF_RES + i*2 + 1];
            tl += loss / fmaxf(cnt, 1.0f);   // ALPHA = 1
            tc += cnt;
        }
        out[0] = tl / (float)NIMG;
        out[1] = tc / (float)NIMG;
    }
}

extern "C" void kernel_launch(void* const* d_in, const int* in_sizes, int n_in,
                              void* d_out, int out_size, void* d_ws, size_t ws_size,
                              hipStream_t stream) {
    const float* inputs  = (const float*)d_in[0];
    const float* targets = (const float*)d_in[1];
    const float* images  = (const float*)d_in[2];
    const float* depth   = (const float*)d_in[3];
    float* out = (float*)d_out;

    float* ws     = (float*)d_ws;
    float4* recsA = (float4*)((char*)d_ws + 65536);
    float4* recsB = recsA + (size_t)NIMG * PAIRS;

    hipLaunchKernelGGL(edgemax_kernel, dim3(NSTRIPS/4, NIMG), dim3(256), 0, stream,
                       images, ws + OFF_EDGE);
    hipLaunchKernelGGL(sample_kernel, dim3(S1BLOCKS, NIMG), dim3(256), 0, stream,
                       inputs, targets, images, depth, ws, recsA, recsB);
    hipLaunchKernelGGL(finish_kernel, dim3(NIMG), dim3(256), 0, stream,
                       ws, recsA, recsB);
    hipLaunchKernelGGL(finalize_kernel, dim3(1), dim3(64), 0, stream, ws, out);
}

// Round 8
// 44.414 us; speedup vs baseline: 1.8124x; 1.2651x over previous
//
#include <hip/hip_runtime.h>
#include <math.h>
#include <stdint.h>

#define NIMG 8
#define HH 1024
#define WW 1024
#define NPIX (HH*WW)
#define PAIRS 10000
#define STRIP 8
#define NSTRIPS 128          // strips per image (rows 1..1022, 8 rows each)
#define S1BLOCKS 40          // sample blocks per image
#define WSLOTS (S1BLOCKS*4)  // per-wave partial slots per image (160)
#define FBLK 4               // finish blocks per image
#define QPAIRS (PAIRS/FBLK)  // 2500

// ws layout (floats):
// [OFF_EDGE .. +NIMG*NSTRIPS)  per-strip squared-sobel max   (1024)   plain stores
// [OFF_MD   .. +NIMG*WSLOTS)   per-wave maxdiff partials     (1280)   plain stores
// [OFF_RES  .. +16)            per-image {loss, cnt} atomic accum (zeroed by edgemax)
// [OFF_CTR]                    finish completion counter (uint, zeroed by edgemax)
// byte 65536:                recsA [NIMG*PAIRS] float4 (d2_0,d2_1,d2_2,un)
// byte 65536+NIMG*PAIRS*16:  recsB [NIMG*PAIRS] float4 (ad_0,ad_1,ad_2,cnt)
#define OFF_EDGE 0
#define OFF_MD   1024
#define OFF_RES  4096
#define OFF_CTR  4112

__device__ __forceinline__ uint64_t mix64(uint64_t x){
    x += 0x9E3779B97F4A7C15ull;
    x = (x ^ (x >> 30)) * 0xBF58476D1CE4E5B9ull;
    x = (x ^ (x >> 27)) * 0x94D049BB133111EBull;
    return x ^ (x >> 31);
}

__device__ __forceinline__ float block_reduce_max(float v, float* sm){
    for (int off = 32; off; off >>= 1)
        v = fmaxf(v, __shfl_down(v, off));
    int wv = threadIdx.x >> 6, lane = threadIdx.x & 63;
    int nw = blockDim.x >> 6;
    if (lane == 0) sm[wv] = v;
    __syncthreads();
    if (threadIdx.x == 0){
        float m = sm[0];
        for (int i = 1; i < nw; ++i) m = fmaxf(m, sm[i]);
        sm[0] = m;
    }
    __syncthreads();
    float r = sm[0];
    __syncthreads();
    return r;
}

__device__ __forceinline__ float block_reduce_sum(float v, float* sm){
    for (int off = 32; off; off >>= 1)
        v += __shfl_down(v, off);
    int wv = threadIdx.x >> 6, lane = threadIdx.x & 63;
    int nw = blockDim.x >> 6;
    if (lane == 0) sm[wv] = v;
    __syncthreads();
    if (threadIdx.x == 0){
        float m = sm[0];
        for (int i = 1; i < nw; ++i) m += sm[i];
        sm[0] = m;
    }
    __syncthreads();
    float r = sm[0];
    __syncthreads();
    return r;
}

__device__ __forceinline__ void sobel_at(const float* __restrict__ x, int r, int c,
                                         float& gx, float& gy){
    const float* p0 = x + (size_t)(r-1)*WW + c;
    const float* p1 = x + (size_t)r*WW + c;
    const float* p2 = x + (size_t)(r+1)*WW + c;
    float a = p0[-1], b = p0[0], cc = p0[1];
    float d = p1[-1],             e = p1[1];
    float f = p2[-1], g = p2[0], h = p2[1];
    gx = (cc - a) + 2.0f*(e - d) + (h - f);
    gy = (a + 2.0f*b + cc) - (f + 2.0f*g + h);
}

__device__ __forceinline__ void load16(const float* __restrict__ p, float* d){
    const float4* q = (const float4*)p;
    float4 v0 = q[0], v1 = q[1], v2 = q[2], v3 = q[3];
    d[0]=v0.x; d[1]=v0.y; d[2]=v0.z; d[3]=v0.w;
    d[4]=v1.x; d[5]=v1.y; d[6]=v1.z; d[7]=v1.w;
    d[8]=v2.x; d[9]=v2.y; d[10]=v2.z; d[11]=v2.w;
    d[12]=v3.x; d[13]=v3.y; d[14]=v3.z; d[15]=v3.w;
}

// One wave owns a 1024-wide row span (16 cols/lane), rolls 3 rows in registers,
// separable sobel, cross-lane neighbors via shuffles, max of SQUARED magnitude.
// Block (0,0) also zeroes the atomic accumulator slots for this launch
// (inter-kernel visibility is guaranteed at dispatch boundaries).
__global__ __launch_bounds__(256) void edgemax_kernel(const float* __restrict__ images,
                                                      float* __restrict__ ws){
    if (blockIdx.x == 0 && blockIdx.y == 0 && threadIdx.x < 17)
        ws[OFF_RES + threadIdx.x] = 0.0f;      // 16 res slots + ctr

    int img  = blockIdx.y;
    const float* x = images + (size_t)img * 3 * NPIX;   // channel 0
    int wv   = threadIdx.x >> 6;
    int lane = threadIdx.x & 63;
    int strip = blockIdx.x * 4 + wv;                    // 0..127
    int r0 = 1 + strip * STRIP;
    int r1 = min(r0 + STRIP - 1, HH - 2);
    int c0 = lane * 16;

    float a[16], b[16], n[16];
    load16(x + (size_t)(r0-1)*WW + c0, a);
    load16(x + (size_t)r0*WW + c0, b);

    float m = 0.0f;
    for (int r = r0; r <= r1; ++r){
        load16(x + (size_t)(r+1)*WW + c0, n);
        float sx[16], dy[16];
        #pragma unroll
        for (int i = 0; i < 16; ++i){
            sx[i] = a[i] + 2.0f*b[i] + n[i];
            dy[i] = a[i] - n[i];
        }
        float sxl = __shfl_up(sx[15], 1);
        float sxr = __shfl_down(sx[0], 1);
        float dyl = __shfl_up(dy[15], 1);
        float dyr = __shfl_down(dy[0], 1);
        #pragma unroll
        for (int j = 0; j < 16; ++j){
            float sl = (j == 0)  ? sxl : sx[j-1];
            float sr = (j == 15) ? sxr : sx[j+1];
            float dl = (j == 0)  ? dyl : dy[j-1];
            float dr = (j == 15) ? dyr : dy[j+1];
            float gx = sr - sl;
            float gy = dl + 2.0f*dy[j] + dr;
            float e2 = gx*gx + gy*gy;
            int c = c0 + j;
            if (c >= 1 && c <= WW-2) m = fmaxf(m, e2);
        }
        #pragma unroll
        for (int i = 0; i < 16; ++i){ a[i] = b[i]; b[i] = n[i]; }
    }
    for (int off = 32; off; off >>= 1)
        m = fmaxf(m, __shfl_down(m, off));
    if (lane == 0)
        ws[OFF_EDGE + img * NSTRIPS + strip] = m;
}

// 1 thread per pair, serial rejection (line-minimal). Single pass:
// classification spilled to records so no second scattered pass is needed.
__global__ __launch_bounds__(256) void sample_kernel(
                               const float* __restrict__ inputs,
                               const float* __restrict__ targets,
                               const float* __restrict__ images,
                               const float* __restrict__ depth_gt,
                               float* __restrict__ ws,
                               float4* __restrict__ recsA,
                               float4* __restrict__ recsB){
    __shared__ float sred[4];
    int img = blockIdx.y;
    int jb  = blockIdx.x;
    int tid = threadIdx.x;
    int j   = jb * 256 + tid;
    const float* x   = images   + (size_t)img * 3 * NPIX;
    const float* inp = inputs   + (size_t)img * NPIX;
    const float* tgt = targets  + (size_t)img * NPIX;
    const float* dgt = depth_gt + (size_t)img * NPIX;

    float ev = 0.0f;
    if (tid < NSTRIPS) ev = ws[OFF_EDGE + img * NSTRIPS + tid];
    float thr2 = 0.01f * block_reduce_max(ev, sred);

    float mdiff = 0.0f;
    float4 recA = make_float4(0.f, 0.f, 0.f, 0.f);   // d2[3], un
    float4 recB = make_float4(0.f, 0.f, 0.f, 0.f);   // ad[3], cnt

    if (j < PAIRS){
        uint64_t base = ((uint64_t)(img * PAIRS + j)) << 10;
        bool pdir = (mix64(((uint64_t)(NIMG * PAIRS + img)) << 10) & 1ull) != 0ull;

        int sh = -1, sw = -1;
        float gxs = 0.f, gys = 0.f, e2s = 1.f;
        for (int att = 0; att < 900; ++att){
            uint64_t u = mix64(base + (uint64_t)att);
            uint32_t pix = (uint32_t)(u >> 44);       // 20-bit uniform
            int r = (int)(pix >> 10);
            int c = (int)(pix & (WW - 1));
            if (r == 0 || r >= HH-1 || c == 0 || c >= WW-1) continue;
            float gx, gy;
            sobel_at(x, r, c, gx, gy);
            float e2 = gx*gx + gy*gy;
            if (!(e2 >= thr2)) continue;
            float dg = dgt[r*WW + c];
            float tg = tgt[r*WW + c];
            if (!(dg > -0.001f && dg < 80.0f && tg != 80.0f)) continue;
            sh = r; sw = c; gxs = gx; gys = gy; e2s = e2;
            break;
        }

        if (sh >= 0){
            float inv = rsqrtf(e2s);
            float cmul = gxs * inv;
            float rmul = gys * inv;
            if (!pdir) cmul = -cmul;

            uint64_t u0 = mix64(base + 1000ull);
            uint64_t u1 = mix64(base + 1001ull);
            float dist[4];
            dist[0] = -(float)(2u + (uint32_t)(u0 & 0xFFFFFFFFull) % 29u);
            dist[1] = -(float)(2u + (uint32_t)(u0 >> 32) % 29u);
            dist[2] =  (float)(2u + (uint32_t)(u1 & 0xFFFFFFFFull) % 29u);
            dist[3] =  (float)(2u + (uint32_t)(u1 >> 32) % 29u);

            int rowc[4], colc[4];
            bool valid = true;
            #pragma unroll
            for (int k = 0; k < 4; ++k){
                int cc2 = sw + (int)rintf(dist[k] * cmul);
                int rr2 = sh + (int)rintf(dist[k] * rmul);
                if (cc2 < 0 || cc2 > WW-1 || rr2 < 0 || rr2 > HH-1) valid = false;
                colc[k] = min(max(cc2, 0), WW-1);
                rowc[k] = min(max(rr2, 0), HH-1);
            }

            if (valid){
                float t4[4], i4[4];
                #pragma unroll
                for (int k = 0; k < 4; ++k){
                    int p = rowc[k]*WW + colc[k];
                    t4[k] = tgt[p];
                    i4[k] = inp[p];
                }
                float d2a[3], ada[3];
                float un = 0.0f;
                #pragma unroll
                for (int k = 0; k < 3; ++k){
                    float tA = t4[k], tB = t4[k+1];
                    float ratio = (tA + 1e-6f) / (tB + 1e-6f);
                    float adk = fabsf(tA - tB);
                    mdiff = fmaxf(mdiff, adk);
                    bool eq = (ratio < 1.03f) && (ratio > 0.9708737864077669f);
                    if (eq){
                        float d = i4[k] - i4[k+1];
                        d2a[k] = d*d; ada[k] = adk;
                    } else {
                        d2a[k] = 0.f; ada[k] = 0.f;
                        float lab = (ratio >= 1.03f) ? 1.0f : -1.0f;
                        un += log1pf(expf((i4[k+1] - i4[k]) * lab));
                    }
                }
                recA = make_float4(d2a[0], d2a[1], d2a[2], un);
                recB = make_float4(ada[0], ada[1], ada[2], 3.0f);
            }
        }
        recsA[img * PAIRS + j] = recA;
        recsB[img * PAIRS + j] = recB;
    }

    for (int off = 32; off; off >>= 1)
        mdiff = fmaxf(mdiff, __shfl_down(mdiff, off));
    if ((tid & 63) == 0)
        ws[OFF_MD + img * WSLOTS + jb*4 + (tid >> 6)] = mdiff;
}

// 4 blocks per image: redundant md reduce, quarter-scan of records, atomic
// accumulation into per-image slots; the LAST block (completion counter)
// performs the final cross-image reduce. All cross-block communication is
// device-scope atomics (coherent) — no plain-store cross-XCD reads.
__global__ __launch_bounds__(256) void finish_kernel(
                               float* __restrict__ ws,
                               const float4* __restrict__ recsA,
                               const float4* __restrict__ recsB,
                               float* __restrict__ out){
    __shared__ float sred[4];
    __shared__ unsigned lastflag;
    int img = blockIdx.x >> 2;
    int q   = blockIdx.x & 3;
    int tid = threadIdx.x;

    float mv = 0.0f;
    if (tid < WSLOTS) mv = ws[OFF_MD + img * WSLOTS + tid];
    float md = block_reduce_max(mv, sred);
    float inv = 1.0f / (md + 1e-6f);

    float loss = 0.0f, cnt = 0.0f;
    int base = img * PAIRS + q * QPAIRS;
    for (int r = tid; r < QPAIRS; r += 256){
        float4 A = recsA[base + r];
        float4 B = recsB[base + r];
        loss += A.w
              + A.x * expf(-B.x * inv)
              + A.y * expf(-B.y * inv)
              + A.z * expf(-B.z * inv);
        cnt  += B.w;
    }
    loss = block_reduce_sum(loss, sred);
    cnt  = block_reduce_sum(cnt, sred);

    if (tid == 0){
        atomicAdd(&ws[OFF_RES + img*2 + 0], loss);
        atomicAdd(&ws[OFF_RES + img*2 + 1], cnt);
        __threadfence();                               // release
        unsigned old = atomicAdd((unsigned int*)&ws[OFF_CTR], 1u);
        lastflag = (old == (unsigned)(NIMG*FBLK - 1)) ? 1u : 0u;
    }
    __syncthreads();

    if (lastflag){
        __threadfence();                               // acquire
        float val = 0.0f, cv = 0.0f;
        if (tid < NIMG){
            float li = atomicAdd(&ws[OFF_RES + tid*2 + 0], 0.0f);  // coherent read
            float ci = atomicAdd(&ws[OFF_RES + tid*2 + 1], 0.0f);
            val = li / fmaxf(ci, 1.0f);
            cv  = ci;
        }
        for (int off = 4; off; off >>= 1){
            val += __shfl_down(val, off);
            cv  += __shfl_down(cv,  off);
        }
        if (tid == 0){
            out[0] = val / (float)NIMG;   // ALPHA = 1
            out[1] = cv  / (float)NIMG;
        }
    }
}

extern "C" void kernel_launch(void* const* d_in, const int* in_sizes, int n_in,
                              void* d_out, int out_size, void* d_ws, size_t ws_size,
                              hipStream_t stream) {
    const float* inputs  = (const float*)d_in[0];
    const float* targets = (const float*)d_in[1];
    const float* images  = (const float*)d_in[2];
    const float* depth   = (const float*)d_in[3];
    float* out = (float*)d_out;

    float* ws     = (float*)d_ws;
    float4* recsA = (float4*)((char*)d_ws + 65536);
    float4* recsB = recsA + (size_t)NIMG * PAIRS;

    hipLaunchKernelGGL(edgemax_kernel, dim3(NSTRIPS/4, NIMG), dim3(256), 0, stream,
                       images, ws);
    hipLaunchKernelGGL(sample_kernel, dim3(S1BLOCKS, NIMG), dim3(256), 0, stream,
                       inputs, targets, images, depth, ws, recsA, recsB);
    hipLaunchKernelGGL(finish_kernel, dim3(NIMG*FBLK), dim3(256), 0, stream,
                       ws, recsA, recsB, out);
}